// Round 9
// baseline (223.873 us; speedup 1.0000x reference)
//
#include <hip/hip_runtime.h>
#include <math.h>

typedef short s16x8 __attribute__((ext_vector_type(8)));
typedef short s16x4 __attribute__((ext_vector_type(4)));
typedef float f32x4 __attribute__((ext_vector_type(4)));

// ws float-offsets
#define POOLED_OFF 0           // 2048*80 = 163840 floats
#define W1PK_OFF   163840      // 128 rows x {w1c0,w1c1,w1c2,b1} = 512 floats
#define B2PK_OFF   164352      // 112 floats (zero-padded)
#define B3PK_OFF   164464      // 80 floats
#define WSHORT_OFF 164560      // short region starts here (16B aligned)
// short-offsets inside short region (frag-ordered, per (n,ks): 512 shorts)
#define W2H_S 0                // 7*4*512 = 14336
#define W2L_S 14336
#define W3H_S 28672            // 5*4*512 = 10240
#define W3L_S 38912

__device__ __forceinline__ void bsplit(float x, short& hi, short& lo) {
    unsigned u  = __float_as_uint(x);
    unsigned uh = u & 0xFFFF0000u;
    hi = (short)(uh >> 16);
    float r = x - __uint_as_float(uh);
    lo = (short)(__float_as_uint(r) >> 16);
}

// Prep (R3-verified): zero pooled, pack w1/b1 rows, pad biases, frag-ordered
// split weights. Frag (n,ks): lane=ln+16*l4 holds w[16n+ln][ks*32+l4*8+j].
__global__ void ds_prep(const float* __restrict__ pw1, const float* __restrict__ pb1,
                        const float* __restrict__ pw2, const float* __restrict__ pb2,
                        const float* __restrict__ pw3, const float* __restrict__ pb3,
                        float* __restrict__ wsF, short* __restrict__ wsS) {
    int t = blockIdx.x * 256 + threadIdx.x;
    if (t < 40960) { f32x4 z = 0.f; *(f32x4*)(wsF + POOLED_OFF + t * 4) = z; return; }
    t -= 40960;
    if (t < 128) {
        f32x4 v = 0.f;
        if (t < 120) { v.x = pw1[t*3]; v.y = pw1[t*3+1]; v.z = pw1[t*3+2]; v.w = pb1[t]; }
        *(f32x4*)(wsF + W1PK_OFF + t * 4) = v; return;
    }
    t -= 128;
    if (t < 112) { wsF[B2PK_OFF + t] = (t < 100) ? pb2[t] : 0.f; return; }
    t -= 112;
    if (t < 80)  { wsF[B3PK_OFF + t] = pb3[t]; return; }
    t -= 80;
    if (t < 14336) {
        int j = t & 7, lane = (t >> 3) & 63, c = t >> 9;
        int ks = c & 3, n = c >> 2;
        int ln = lane & 15, l4 = lane >> 4;
        int row = 16 * n + ln, col = ks * 32 + l4 * 8 + j;
        float v = (row < 100 && col < 120) ? pw2[row * 120 + col] : 0.f;
        short hi, lo; bsplit(v, hi, lo);
        wsS[W2H_S + t] = hi; wsS[W2L_S + t] = lo; return;
    }
    t -= 14336;
    if (t < 10240) {
        int j = t & 7, lane = (t >> 3) & 63, c = t >> 9;
        int ks = c & 3, n = c >> 2;
        int ln = lane & 15, l4 = lane >> 4;
        int row = 16 * n + ln, col = ks * 32 + l4 * 8 + j;
        float v = (col < 100) ? pw3[row * 100 + col] : 0.f;
        short hi, lo; bsplit(v, hi, lo);
        wsS[W3H_S + t] = hi; wsS[W3L_S + t] = lo; return;
    }
}

#define MFMA_B16(A, B, C) __builtin_amdgcn_mfma_f32_16x16x32_bf16((A), (B), (C), 0, 0, 0)

// Phi: grid (4 el-blocks, B batches) x 512 thr. Block computes 32 els of one
// batch: h1 -> LDS (XOR-swizzled) -> L2 (waves 0-6 own o-tiles) -> h2 LDS ->
// L3 (waves 0-4 own o3-tiles) + in-reg pool -> global atomicAdd. No loops ->
// no LICM hoisting -> no spills. 32 KB LDS -> 4 blocks/CU.
__global__ __launch_bounds__(512)
void ds_phi(const float* __restrict__ dyn, const float* __restrict__ wsF,
            const short* __restrict__ wsS, float* __restrict__ pooledG) {
    const int tid = threadIdx.x;
    const int w = tid >> 6, l = tid & 63, ln = l & 15, l4 = l >> 4;
    const int eb = blockIdx.x;
    const int b  = blockIdx.y;

    __shared__ short h1H[4096], h1L[4096];   // [32 el][128 k], k ^= (el&7)<<3
    __shared__ short h2H[4096], h2L[4096];   // [32 el][128 o], o ^= (el&7)<<3

    const short* w2h = wsS + W2H_S;
    const short* w2l = wsS + W2L_S;
    const short* w3h = wsS + W3H_S;
    const short* w3l = wsS + W3L_S;

    // ---- phase 0: h1 gen (1 task/thread) + zero h2 pad rows o=112..127 ----
    {
        const int row = tid >> 4, kg = tid & 15, k0 = kg * 8;
        const int el = eb * 32 + row;
        const float* xp = dyn + (size_t)b * 384 + el * 3;
        const float x0 = xp[0], x1 = xp[1], x2 = xp[2];
        s16x8 vh, vl;
        #pragma unroll
        for (int j = 0; j < 8; ++j) {
            f32x4 c = *(const f32x4*)(wsF + W1PK_OFF + (k0 + j) * 4);
            float v = fmaf(x0, c.x, fmaf(x1, c.y, fmaf(x2, c.z, c.w)));
            v = fmaxf(v, 0.f);
            short hi, lo; bsplit(v, hi, lo);
            vh[j] = hi; vl[j] = lo;
        }
        const int idx = row * 128 + (k0 ^ ((row & 7) << 3));
        *(s16x8*)(h1H + idx) = vh;
        *(s16x8*)(h1L + idx) = vl;
        if (tid < 128) {
            const int r2 = tid >> 2, og = tid & 3;
            const int o0 = 112 + (og & 1) * 8;
            short* dst = (og < 2) ? h2H : h2L;
            s16x8 z = 0;
            *(s16x8*)(dst + r2 * 128 + (o0 ^ ((r2 & 7) << 3))) = z;
        }
    }
    __syncthreads();

    // ---- phase 1: L2, wave w owns o-tile n2=w (w<7); el-tiles t=0,1 ----
    if (w < 7) {
        const int n2 = w;
        #define L2TILE(T) do {                                                      \
            const int row = 16 * (T) + ln;                                          \
            const int swz = (row & 7) << 3;                                         \
            f32x4 a2h = 0.f, a2x = 0.f;                                             \
            _Pragma("unroll")                                                       \
            for (int ks = 0; ks < 4; ++ks) {                                        \
                const s16x8 ah = *(const s16x8*)(w2h + ((n2 * 4 + ks) * 64 + l) * 8);\
                const s16x8 al = *(const s16x8*)(w2l + ((n2 * 4 + ks) * 64 + l) * 8);\
                const int bidx = row * 128 + ((ks * 32 + l4 * 8) ^ swz);            \
                const s16x8 bh = *(const s16x8*)(h1H + bidx);                       \
                const s16x8 bl = *(const s16x8*)(h1L + bidx);                       \
                a2h = MFMA_B16(ah, bh, a2h);                                        \
                a2x = MFMA_B16(ah, bl, a2x);                                        \
                a2x = MFMA_B16(al, bh, a2x);                                        \
            }                                                                       \
            const int o0 = 16 * n2 + 4 * l4;                                        \
            const f32x4 bb = *(const f32x4*)(wsF + B2PK_OFF + o0);                  \
            s16x4 oh, ol;                                                           \
            _Pragma("unroll")                                                       \
            for (int r = 0; r < 4; ++r) {                                           \
                float v = fmaxf(a2h[r] + a2x[r] + bb[r], 0.f);                      \
                short hi, lo; bsplit(v, hi, lo);                                    \
                oh[r] = hi; ol[r] = lo;                                             \
            }                                                                       \
            const int idx2 = row * 128 + (o0 ^ swz);                                \
            *(s16x4*)(h2H + idx2) = oh;                                             \
            *(s16x4*)(h2L + idx2) = ol;                                             \
        } while (0)
        L2TILE(0);
        L2TILE(1);
        #undef L2TILE
    }
    __syncthreads();

    // ---- phase 2: L3, wave w owns o3-tile n3=w (w<5); pool over el in regs ----
    if (w < 5) {
        const int n3 = w;
        float pool0 = 0.f, pool1 = 0.f, pool2 = 0.f, pool3 = 0.f;
        const f32x4 bb3 = *(const f32x4*)(wsF + B3PK_OFF + 16 * n3 + 4 * l4);
        #define L3TILE(T) do {                                                      \
            const int row = 16 * (T) + ln;                                          \
            const int swz = (row & 7) << 3;                                         \
            f32x4 a3 = 0.f, a3x = 0.f;                                              \
            _Pragma("unroll")                                                       \
            for (int ks = 0; ks < 4; ++ks) {                                        \
                const s16x8 ah = *(const s16x8*)(w3h + ((n3 * 4 + ks) * 64 + l) * 8);\
                const s16x8 al = *(const s16x8*)(w3l + ((n3 * 4 + ks) * 64 + l) * 8);\
                const int bidx = row * 128 + ((ks * 32 + l4 * 8) ^ swz);            \
                const s16x8 bh = *(const s16x8*)(h2H + bidx);                       \
                const s16x8 bl = *(const s16x8*)(h2L + bidx);                       \
                a3  = MFMA_B16(ah, bh, a3);                                         \
                a3x = MFMA_B16(ah, bl, a3x);                                        \
                a3x = MFMA_B16(al, bh, a3x);                                        \
            }                                                                       \
            pool0 += fmaxf(a3[0] + a3x[0] + bb3[0], 0.f);                           \
            pool1 += fmaxf(a3[1] + a3x[1] + bb3[1], 0.f);                           \
            pool2 += fmaxf(a3[2] + a3x[2] + bb3[2], 0.f);                           \
            pool3 += fmaxf(a3[3] + a3x[3] + bb3[3], 0.f);                           \
        } while (0)
        L3TILE(0);
        L3TILE(1);
        #undef L3TILE
        // reduce over ln (16 els per tile already summed across tiles in regs)
        #pragma unroll
        for (int d = 1; d < 16; d <<= 1) {
            pool0 += __shfl_xor(pool0, d);
            pool1 += __shfl_xor(pool1, d);
            pool2 += __shfl_xor(pool2, d);
            pool3 += __shfl_xor(pool3, d);
        }
        if (ln == 0) {
            float* pb = pooledG + (size_t)b * 80 + 16 * n3 + 4 * l4;
            atomicAdd(pb + 0, pool0);
            atomicAdd(pb + 1, pool1);
            atomicAdd(pb + 2, pool2);
            atomicAdd(pb + 3, pool3);
        }
    }
}

// Tail (R3-verified): one 256-thread block per batch, no loops.
__global__ __launch_bounds__(256, 4)
void ds_tail(const float* __restrict__ pooledG, const float* __restrict__ stat,
             const float* __restrict__ rw1, const float* __restrict__ rb1,
             const float* __restrict__ rw2, const float* __restrict__ rb2,
             const float* __restrict__ rw3, const float* __restrict__ rb3,
             const float* __restrict__ qw1, const float* __restrict__ qb1,
             const float* __restrict__ qw2, const float* __restrict__ qb2,
             const float* __restrict__ qw3, const float* __restrict__ qb3,
             float* __restrict__ out) {
    const int b = blockIdx.x, tid = threadIdx.x;
    __shared__ __align__(16) float r1s[64], r2s[64], xcat[48], q1s[200], q2s[104];
    __shared__ float logits[3];
    const float* pooled = pooledG + (size_t)b * 80;

    if (tid < 60) {
        float a = rb1[tid];
        for (int k = 0; k < 80; k += 4) {
            f32x4 pv = *(const f32x4*)(pooled + k);
            f32x4 wv = *(const f32x4*)(rw1 + tid * 80 + k);
            a += pv.x * wv.x + pv.y * wv.y + pv.z * wv.z + pv.w * wv.w;
        }
        r1s[tid] = fmaxf(a, 0.0f);
    }
    __syncthreads();
    if (tid < 60) {
        float a = rb2[tid];
        for (int k = 0; k < 60; k += 4) {
            f32x4 pv = *(const f32x4*)(r1s + k);
            f32x4 wv = *(const f32x4*)(rw2 + tid * 60 + k);
            a += pv.x * wv.x + pv.y * wv.y + pv.z * wv.z + pv.w * wv.w;
        }
        r2s[tid] = fmaxf(a, 0.0f);
    }
    __syncthreads();
    if (tid < 40) {
        float a = rb3[tid];
        for (int k = 0; k < 60; k += 4) {
            f32x4 pv = *(const f32x4*)(r2s + k);
            f32x4 wv = *(const f32x4*)(rw3 + tid * 60 + k);
            a += pv.x * wv.x + pv.y * wv.y + pv.z * wv.z + pv.w * wv.w;
        }
        xcat[tid] = a;
    }
    if (tid >= 40 && tid < 43) xcat[tid] = stat[(size_t)b * 3 + (tid - 40)];
    __syncthreads();
    if (tid < 200) {
        float a = qb1[tid];
        const float* wv = qw1 + tid * 43;
        for (int k = 0; k < 43; ++k) a += xcat[k] * wv[k];
        q1s[tid] = fmaxf(a, 0.0f);
    }
    __syncthreads();
    if (tid < 100) {
        float a = qb2[tid];
        for (int k = 0; k < 200; k += 4) {
            f32x4 pv = *(const f32x4*)(q1s + k);
            f32x4 wv = *(const f32x4*)(qw2 + tid * 200 + k);
            a += pv.x * wv.x + pv.y * wv.y + pv.z * wv.z + pv.w * wv.w;
        }
        q2s[tid] = fmaxf(a, 0.0f);
    }
    __syncthreads();
    if (tid < 96) {
        int o = tid >> 5, l2 = tid & 31;
        float a = 0.0f;
        for (int k = l2; k < 100; k += 32) a += q2s[k] * qw3[o * 100 + k];
        #pragma unroll
        for (int d = 16; d > 0; d >>= 1) a += __shfl_down(a, d, 32);
        if (l2 == 0) logits[o] = a + qb3[o];
    }
    __syncthreads();
    if (tid < 3) {
        float l0 = logits[0], l1 = logits[1], l2v = logits[2];
        float m  = fmaxf(l0, fmaxf(l1, l2v));
        float e0 = __expf(l0 - m), e1 = __expf(l1 - m), e2 = __expf(l2v - m);
        float inv = 1.0f / (e0 + e1 + e2);
        float mine = (tid == 0) ? e0 : ((tid == 1) ? e1 : e2);
        out[(size_t)b * 3 + tid] = mine * inv;
    }
}

extern "C" void kernel_launch(void* const* d_in, const int* in_sizes, int n_in,
                              void* d_out, int out_size, void* d_ws, size_t ws_size,
                              hipStream_t stream) {
    const float* dyn  = (const float*)d_in[0];
    const float* stat = (const float*)d_in[1];
    const float* pw1  = (const float*)d_in[2];
    const float* pb1  = (const float*)d_in[3];
    const float* pw2  = (const float*)d_in[4];
    const float* pb2  = (const float*)d_in[5];
    const float* pw3  = (const float*)d_in[6];
    const float* pb3  = (const float*)d_in[7];
    const float* rw1  = (const float*)d_in[8];
    const float* rb1  = (const float*)d_in[9];
    const float* rw2  = (const float*)d_in[10];
    const float* rb2  = (const float*)d_in[11];
    const float* rw3  = (const float*)d_in[12];
    const float* rb3  = (const float*)d_in[13];
    const float* qw1  = (const float*)d_in[14];
    const float* qb1  = (const float*)d_in[15];
    const float* qw2  = (const float*)d_in[16];
    const float* qb2  = (const float*)d_in[17];
    const float* qw3  = (const float*)d_in[18];
    const float* qb3  = (const float*)d_in[19];
    float* out = (float*)d_out;

    float* wsF = (float*)d_ws;
    short* wsS = (short*)(wsF + WSHORT_OFF);
    float* pooledG = wsF + POOLED_OFF;
    const int B = in_sizes[0] / 384;   // 2048

    ds_prep<<<dim3(258), dim3(256), 0, stream>>>(pw1, pb1, pw2, pb2, pw3, pb3, wsF, wsS);
    ds_phi<<<dim3(4, B), dim3(512), 0, stream>>>(dyn, wsF, wsS, pooledG);
    ds_tail<<<dim3(B), dim3(256), 0, stream>>>(pooledG, stat,
        rw1, rb1, rw2, rb2, rw3, rb3,
        qw1, qb1, qw2, qb2, qw3, qb3, out);
}

// Round 10
// 190.610 us; speedup vs baseline: 1.1745x; 1.1745x over previous
//
#include <hip/hip_runtime.h>
#include <math.h>

typedef short s16x8 __attribute__((ext_vector_type(8)));
typedef short s16x4 __attribute__((ext_vector_type(4)));
typedef float f32x4 __attribute__((ext_vector_type(4)));

__device__ __forceinline__ void bsplit(float x, short& hi, short& lo) {
    unsigned u  = __float_as_uint(x);
    unsigned uh = u & 0xFFFF0000u;
    hi = (short)(uh >> 16);
    float r = x - __uint_as_float(uh);
    lo = (short)(__float_as_uint(r) >> 16);
}

#define MFMA_B16(A, B, C) __builtin_amdgcn_mfma_f32_16x16x32_bf16((A), (B), (C), 0, 0, 0)

// Single fused kernel: 1 batch per block, 512 thr (8 waves).
// Weight-stationary: wave w<7 holds w2 o-tile frags in regs; w<5 also w3 frags.
// Loop over 8 el-tiles: gen h1(16el) -> LDS -> L2 -> h2 LDS -> L3 + reg pool.
// No global loads inside the loop => LICM cannot create spill pressure.
__global__ __launch_bounds__(512, 4)
void ds_all(const float* __restrict__ dyn, const float* __restrict__ stat,
            const float* __restrict__ pw1, const float* __restrict__ pb1,
            const float* __restrict__ pw2, const float* __restrict__ pb2,
            const float* __restrict__ pw3, const float* __restrict__ pb3,
            const float* __restrict__ rw1, const float* __restrict__ rb1,
            const float* __restrict__ rw2, const float* __restrict__ rb2,
            const float* __restrict__ rw3, const float* __restrict__ rb3,
            const float* __restrict__ qw1, const float* __restrict__ qb1,
            const float* __restrict__ qw2, const float* __restrict__ qb2,
            const float* __restrict__ qw3, const float* __restrict__ qb3,
            float* __restrict__ out) {
    const int tid = threadIdx.x;
    const int w = tid >> 6, l = tid & 63, ln = l & 15, l4 = l >> 4;
    const int b = blockIdx.x;

    __shared__ __align__(16) float xs[384];
    __shared__ short h1H[2048], h1L[2048];   // [16 el][128 k], col ^= (el&7)<<3
    __shared__ short h2H[2048], h2L[2048];   // [16 el][128 o], col ^= (el&7)<<3
    __shared__ __align__(16) float pooledS[80];
    __shared__ __align__(16) float r1s[64], r2s[64], xcat[48], q1s[200], q2s[104];
    __shared__ float logits[3];

    // ---- stage dyn[b] ----
    if (tid < 96)
        *(f32x4*)(xs + tid * 4) = *(const f32x4*)(dyn + (size_t)b * 384 + tid * 4);

    // ---- zero h2 cols 112..127 (never written; must be finite for MFMA) ----
    if (tid < 128) {
        const int t = tid & 63, row = t >> 2, q = t & 3;
        const int col = (112 + q * 4) ^ ((row & 7) << 3);
        s16x4 z = 0;
        short* dst = (tid < 64) ? h2H : h2L;
        *(s16x4*)(dst + row * 128 + col) = z;
    }

    // ---- per-thread w1 coeffs (h1-gen role: row=tid>>5, k0=(tid&31)*4) ----
    const int grow = tid >> 5;
    const int k0   = (tid & 31) * 4;
    f32x4 c1_0, c1_1, c1_2, c1_3;
    #define LDC(J, C) do { const int k = k0 + (J);                              \
        if (k < 120) { C.x = pw1[k*3]; C.y = pw1[k*3+1]; C.z = pw1[k*3+2];      \
                       C.w = pb1[k]; }                                          \
        else C = 0.f; } while (0)
    LDC(0, c1_0); LDC(1, c1_1); LDC(2, c1_2); LDC(3, c1_3);
    #undef LDC

    // ---- stationary weight frags (A-operand): w2 for w<7, w3 for w<5 ----
    const int arow = 16 * w + ln;
    s16x8 w2h0=0,w2h1=0,w2h2=0,w2h3=0, w2l0=0,w2l1=0,w2l2=0,w2l3=0;
    s16x8 w3h0=0,w3h1=0,w3h2=0,w3h3=0, w3l0=0,w3l1=0,w3l2=0,w3l3=0;
    f32x4 bb2 = 0.f, bb3 = 0.f;
    if (w < 7) {
        #define LDW2(KS, DH, DL) do { s16x8 vh, vl;                             \
            _Pragma("unroll")                                                   \
            for (int j = 0; j < 8; ++j) {                                       \
                const int c = (KS) * 32 + l4 * 8 + j;                           \
                float v = (arow < 100 && c < 120) ? pw2[arow * 120 + c] : 0.f;  \
                short hi, lo; bsplit(v, hi, lo); vh[j] = hi; vl[j] = lo;        \
            } DH = vh; DL = vl; } while (0)
        LDW2(0, w2h0, w2l0); LDW2(1, w2h1, w2l1);
        LDW2(2, w2h2, w2l2); LDW2(3, w2h3, w2l3);
        #undef LDW2
        const int o0 = 16 * w + 4 * l4;
        #pragma unroll
        for (int r = 0; r < 4; ++r) bb2[r] = (o0 + r < 100) ? pb2[o0 + r] : 0.f;
    }
    if (w < 5) {
        #define LDW3(KS, DH, DL) do { s16x8 vh, vl;                             \
            _Pragma("unroll")                                                   \
            for (int j = 0; j < 8; ++j) {                                       \
                const int c = (KS) * 32 + l4 * 8 + j;                           \
                float v = (c < 100) ? pw3[arow * 100 + c] : 0.f;                \
                short hi, lo; bsplit(v, hi, lo); vh[j] = hi; vl[j] = lo;        \
            } DH = vh; DL = vl; } while (0)
        LDW3(0, w3h0, w3l0); LDW3(1, w3h1, w3l1);
        LDW3(2, w3h2, w3l2); LDW3(3, w3h3, w3l3);
        #undef LDW3
        bb3 = *(const f32x4*)(pb3 + 16 * w + 4 * l4);
    }
    __syncthreads();

    float pool0 = 0.f, pool1 = 0.f, pool2 = 0.f, pool3 = 0.f;
    const int swzR = (ln & 7) << 3;         // read-side swizzle (row = ln)
    const int swzG = (grow & 7) << 3;       // gen-side swizzle  (row = grow)

    #pragma unroll 1
    for (int T = 0; T < 8; ++T) {
        // ---- gen h1 tile: thread -> 4 values of row grow, k0..k0+3 ----
        {
            const int el = 16 * T + grow;
            const float x0 = xs[el * 3], x1 = xs[el * 3 + 1], x2 = xs[el * 3 + 2];
            s16x4 vh, vl;
            #define GEN(J, C) do {                                              \
                float v = fmaf(x0, C.x, fmaf(x1, C.y, fmaf(x2, C.z, C.w)));     \
                v = fmaxf(v, 0.f);                                              \
                short hi, lo; bsplit(v, hi, lo); vh[J] = hi; vl[J] = lo;        \
            } while (0)
            GEN(0, c1_0); GEN(1, c1_1); GEN(2, c1_2); GEN(3, c1_3);
            #undef GEN
            const int idx = grow * 128 + (k0 ^ swzG);
            *(s16x4*)(h1H + idx) = vh;
            *(s16x4*)(h1L + idx) = vl;
        }
        __syncthreads();

        // ---- L2: wave w<7 computes h2 o-tile n2=w for this el-tile ----
        if (w < 7) {
            f32x4 a2h = 0.f, a2x = 0.f;
            #define L2K(KS, WH, WL) do {                                        \
                const int bidx = ln * 128 + (((KS) * 32 + l4 * 8) ^ swzR);      \
                const s16x8 bh = *(const s16x8*)(h1H + bidx);                   \
                const s16x8 bl = *(const s16x8*)(h1L + bidx);                   \
                a2h = MFMA_B16(WH, bh, a2h);                                    \
                a2x = MFMA_B16(WH, bl, a2x);                                    \
                a2x = MFMA_B16(WL, bh, a2x);                                    \
            } while (0)
            L2K(0, w2h0, w2l0); L2K(1, w2h1, w2l1);
            L2K(2, w2h2, w2l2); L2K(3, w2h3, w2l3);
            #undef L2K
            s16x4 oh, ol;
            #pragma unroll
            for (int r = 0; r < 4; ++r) {
                float v = fmaxf(a2h[r] + a2x[r] + bb2[r], 0.f);
                short hi, lo; bsplit(v, hi, lo);
                oh[r] = hi; ol[r] = lo;
            }
            const int idx2 = ln * 128 + ((16 * w + 4 * l4) ^ swzR);
            *(s16x4*)(h2H + idx2) = oh;
            *(s16x4*)(h2L + idx2) = ol;
        }
        __syncthreads();

        // ---- L3 + pool: wave w<5 computes o3-tile n3=w, accumulates pool ----
        if (w < 5) {
            f32x4 a3 = 0.f, a3x = 0.f;
            #define L3K(KS, WH, WL) do {                                        \
                const int bidx = ln * 128 + (((KS) * 32 + l4 * 8) ^ swzR);      \
                const s16x8 bh = *(const s16x8*)(h2H + bidx);                   \
                const s16x8 bl = *(const s16x8*)(h2L + bidx);                   \
                a3  = MFMA_B16(WH, bh, a3);                                     \
                a3x = MFMA_B16(WH, bl, a3x);                                    \
                a3x = MFMA_B16(WL, bh, a3x);                                    \
            } while (0)
            L3K(0, w3h0, w3l0); L3K(1, w3h1, w3l1);
            L3K(2, w3h2, w3l2); L3K(3, w3h3, w3l3);
            #undef L3K
            pool0 += fmaxf(a3[0] + a3x[0] + bb3[0], 0.f);
            pool1 += fmaxf(a3[1] + a3x[1] + bb3[1], 0.f);
            pool2 += fmaxf(a3[2] + a3x[2] + bb3[2], 0.f);
            pool3 += fmaxf(a3[3] + a3x[3] + bb3[3], 0.f);
        }
        __syncthreads();
    }

    // ---- pool reduce over ln, write pooledS (each wave owns distinct o's) ----
    if (w < 5) {
        #pragma unroll
        for (int d = 1; d < 16; d <<= 1) {
            pool0 += __shfl_xor(pool0, d);
            pool1 += __shfl_xor(pool1, d);
            pool2 += __shfl_xor(pool2, d);
            pool3 += __shfl_xor(pool3, d);
        }
        if (ln == 0) {
            const int o0 = 16 * w + 4 * l4;
            pooledS[o0 + 0] = pool0;
            pooledS[o0 + 1] = pool1;
            pooledS[o0 + 2] = pool2;
            pooledS[o0 + 3] = pool3;
        }
    }
    __syncthreads();

    // ---- fused tail (rho + q + softmax) ----
    if (tid < 60) {
        float a = rb1[tid];
        for (int k = 0; k < 80; k += 4) {
            f32x4 pv = *(const f32x4*)(pooledS + k);
            f32x4 wv = *(const f32x4*)(rw1 + tid * 80 + k);
            a += pv.x * wv.x + pv.y * wv.y + pv.z * wv.z + pv.w * wv.w;
        }
        r1s[tid] = fmaxf(a, 0.0f);
    }
    __syncthreads();
    if (tid < 60) {
        float a = rb2[tid];
        for (int k = 0; k < 60; k += 4) {
            f32x4 pv = *(const f32x4*)(r1s + k);
            f32x4 wv = *(const f32x4*)(rw2 + tid * 60 + k);
            a += pv.x * wv.x + pv.y * wv.y + pv.z * wv.z + pv.w * wv.w;
        }
        r2s[tid] = fmaxf(a, 0.0f);
    }
    __syncthreads();
    if (tid < 40) {
        float a = rb3[tid];
        for (int k = 0; k < 60; k += 4) {
            f32x4 pv = *(const f32x4*)(r2s + k);
            f32x4 wv = *(const f32x4*)(rw3 + tid * 60 + k);
            a += pv.x * wv.x + pv.y * wv.y + pv.z * wv.z + pv.w * wv.w;
        }
        xcat[tid] = a;
    }
    if (tid >= 40 && tid < 43) xcat[tid] = stat[(size_t)b * 3 + (tid - 40)];
    __syncthreads();
    if (tid < 200) {
        float a = qb1[tid];
        const float* wv = qw1 + tid * 43;
        for (int k = 0; k < 43; ++k) a += xcat[k] * wv[k];
        q1s[tid] = fmaxf(a, 0.0f);
    }
    __syncthreads();
    if (tid < 100) {
        float a = qb2[tid];
        for (int k = 0; k < 200; k += 4) {
            f32x4 pv = *(const f32x4*)(q1s + k);
            f32x4 wv = *(const f32x4*)(qw2 + tid * 200 + k);
            a += pv.x * wv.x + pv.y * wv.y + pv.z * wv.z + pv.w * wv.w;
        }
        q2s[tid] = fmaxf(a, 0.0f);
    }
    __syncthreads();
    if (tid < 96) {
        int o = tid >> 5, l2 = tid & 31;
        float a = 0.0f;
        for (int k = l2; k < 100; k += 32) a += q2s[k] * qw3[o * 100 + k];
        #pragma unroll
        for (int d = 16; d > 0; d >>= 1) a += __shfl_down(a, d, 32);
        if (l2 == 0) logits[o] = a + qb3[o];
    }
    __syncthreads();
    if (tid < 3) {
        float l0 = logits[0], l1 = logits[1], l2v = logits[2];
        float m  = fmaxf(l0, fmaxf(l1, l2v));
        float e0 = __expf(l0 - m), e1 = __expf(l1 - m), e2 = __expf(l2v - m);
        float inv = 1.0f / (e0 + e1 + e2);
        float mine = (tid == 0) ? e0 : ((tid == 1) ? e1 : e2);
        out[(size_t)b * 3 + tid] = mine * inv;
    }
}

extern "C" void kernel_launch(void* const* d_in, const int* in_sizes, int n_in,
                              void* d_out, int out_size, void* d_ws, size_t ws_size,
                              hipStream_t stream) {
    const float* dyn  = (const float*)d_in[0];
    const float* stat = (const float*)d_in[1];
    const float* pw1  = (const float*)d_in[2];
    const float* pb1  = (const float*)d_in[3];
    const float* pw2  = (const float*)d_in[4];
    const float* pb2  = (const float*)d_in[5];
    const float* pw3  = (const float*)d_in[6];
    const float* pb3  = (const float*)d_in[7];
    const float* rw1  = (const float*)d_in[8];
    const float* rb1  = (const float*)d_in[9];
    const float* rw2  = (const float*)d_in[10];
    const float* rb2  = (const float*)d_in[11];
    const float* rw3  = (const float*)d_in[12];
    const float* rb3  = (const float*)d_in[13];
    const float* qw1  = (const float*)d_in[14];
    const float* qb1  = (const float*)d_in[15];
    const float* qw2  = (const float*)d_in[16];
    const float* qb2  = (const float*)d_in[17];
    const float* qw3  = (const float*)d_in[18];
    const float* qb3  = (const float*)d_in[19];
    float* out = (float*)d_out;

    const int B = in_sizes[0] / 384;   // 2048
    ds_all<<<dim3(B), dim3(512), 0, stream>>>(dyn, stat,
        pw1, pb1, pw2, pb2, pw3, pb3,
        rw1, rb1, rw2, rb2, rw3, rb3,
        qw1, qb1, qw2, qb2, qw3, qb3, out);
}